// Round 1
// baseline (382.095 us; speedup 1.0000x reference)
//
#include <hip/hip_runtime.h>

#define NL 5
#define CH 8
#define BATCH 4
#define HH 1024
#define WW 1024
#define HW (HH * WW)
#define TOTAL (BATCH * HW)

struct TexPtrs { const float* t[NL]; };

// Transpose one mip level from (C, R, R) to (R, R, C) interleaved.
// Thread = texel. Reads coalesced per channel; writes 32B contiguous per lane.
__global__ __launch_bounds__(256) void transpose_tex_kernel(
    const float* __restrict__ src, float* __restrict__ dst, int n) {
  int i = blockIdx.x * blockDim.x + threadIdx.x;
  if (i >= n) return;
  float v[CH];
#pragma unroll
  for (int c = 0; c < CH; ++c) v[c] = src[(size_t)c * n + i];
  float4* d = (float4*)(dst + (size_t)i * CH);
  d[0] = make_float4(v[0], v[1], v[2], v[3]);
  d[1] = make_float4(v[4], v[5], v[6], v[7]);
}

template <bool TR>
__global__ __launch_bounds__(256) void neumip_main(
    const float2* __restrict__ uvs, const float* __restrict__ level,
    TexPtrs tp, float* __restrict__ out) {
  int idx = blockIdx.x * blockDim.x + threadIdx.x;
  if (idx >= TOTAL) return;

  float2 uv = uvs[idx];
  float lvl = level[idx];

  // frac = uv - trunc(uv); coords = frac*2 - 1  (replicate reference op order)
  float fu = uv.x - truncf(uv.x);
  float fv = uv.y - truncf(uv.y);
  float cu = fu * 2.0f - 1.0f;
  float cv = fv * 2.0f - 1.0f;

  float fb = floorf(lvl);
  float alpha = lvl - fb;
  fb = fminf(fmaxf(fb, 0.0f), (float)(NL - 1));
  int l0 = (int)fb;
  int l1 = min(l0 + 1, NL - 1);

  float acc[CH];
#pragma unroll
  for (int c = 0; c < CH; ++c) acc[c] = 0.0f;

  int lv[2];
  lv[0] = l0;
  lv[1] = l1;
  float wgt[2];
  wgt[0] = 1.0f - alpha;
  wgt[1] = alpha;

#pragma unroll
  for (int s = 0; s < 2; ++s) {
    int L = lv[s];
    int R = 512 >> L;
    float Rm1 = (float)(R - 1);
    // x = (coords+1)*0.5*(R-1)  (reference op order)
    float x = (cu + 1.0f) * 0.5f * Rm1;
    float y = (cv + 1.0f) * 0.5f * Rm1;
    float x0f = floorf(x);
    float y0f = floorf(y);
    float wx = x - x0f;
    float wy = y - y0f;
    int x0 = (int)x0f;
    int y0 = (int)y0f;
    // In-domain inputs guarantee validity; clamp is a free safety net and
    // matches zero-weight corners (wx/wy==0 when clamping would matter).
    x0 = max(x0, 0);
    y0 = max(y0, 0);
    int x1 = min(x0 + 1, R - 1);
    int y1 = min(y0 + 1, R - 1);

    float w = wgt[s];
    float w00 = (1.0f - wx) * (1.0f - wy) * w;
    float w01 = wx * (1.0f - wy) * w;
    float w10 = (1.0f - wx) * wy * w;
    float w11 = wx * wy * w;

    if (TR) {
      const float4* t = (const float4*)tp.t[L];
      size_t i00 = ((size_t)y0 * R + x0) * 2;
      size_t i01 = ((size_t)y0 * R + x1) * 2;
      size_t i10 = ((size_t)y1 * R + x0) * 2;
      size_t i11 = ((size_t)y1 * R + x1) * 2;
      float4 a00 = t[i00], b00 = t[i00 + 1];
      float4 a01 = t[i01], b01 = t[i01 + 1];
      float4 a10 = t[i10], b10 = t[i10 + 1];
      float4 a11 = t[i11], b11 = t[i11 + 1];
      acc[0] += a00.x * w00 + a01.x * w01 + a10.x * w10 + a11.x * w11;
      acc[1] += a00.y * w00 + a01.y * w01 + a10.y * w10 + a11.y * w11;
      acc[2] += a00.z * w00 + a01.z * w01 + a10.z * w10 + a11.z * w11;
      acc[3] += a00.w * w00 + a01.w * w01 + a10.w * w10 + a11.w * w11;
      acc[4] += b00.x * w00 + b01.x * w01 + b10.x * w10 + b11.x * w11;
      acc[5] += b00.y * w00 + b01.y * w01 + b10.y * w10 + b11.y * w11;
      acc[6] += b00.z * w00 + b01.z * w01 + b10.z * w10 + b11.z * w11;
      acc[7] += b00.w * w00 + b01.w * w01 + b10.w * w10 + b11.w * w11;
    } else {
      const float* t = tp.t[L];
      int n = R * R;
#pragma unroll
      for (int c = 0; c < CH; ++c) {
        const float* tc = t + (size_t)c * n;
        acc[c] += tc[(size_t)y0 * R + x0] * w00 + tc[(size_t)y0 * R + x1] * w01 +
                  tc[(size_t)y1 * R + x0] * w10 + tc[(size_t)y1 * R + x1] * w11;
      }
    }
  }

  // out[b][c][h][w]; idx = b*HW + hw
  int b = idx >> 20;          // HW = 1<<20
  int hw = idx & (HW - 1);
  float* o = out + ((size_t)b * CH) * HW + hw;
#pragma unroll
  for (int c = 0; c < CH; ++c) o[(size_t)c * HW] = acc[c];
}

extern "C" void kernel_launch(void* const* d_in, const int* in_sizes, int n_in,
                              void* d_out, int out_size, void* d_ws, size_t ws_size,
                              hipStream_t stream) {
  const float2* uvs = (const float2*)d_in[0];
  const float* level = (const float*)d_in[1];
  static const int res[NL] = {512, 256, 128, 64, 32};

  // Transposed copies need sum(R^2)*CH floats = 11,173,888 bytes.
  size_t needed = 0;
  for (int n = 0; n < NL; ++n) needed += (size_t)res[n] * res[n] * CH * sizeof(float);

  TexPtrs tp;
  if (ws_size >= needed) {
    float* cur = (float*)d_ws;
    for (int n = 0; n < NL; ++n) {
      int cnt = res[n] * res[n];
      transpose_tex_kernel<<<(cnt + 255) / 256, 256, 0, stream>>>(
          (const float*)d_in[2 + n], cur, cnt);
      tp.t[n] = cur;
      cur += (size_t)cnt * CH;
    }
    neumip_main<true><<<TOTAL / 256, 256, 0, stream>>>(uvs, level, tp, (float*)d_out);
  } else {
    for (int n = 0; n < NL; ++n) tp.t[n] = (const float*)d_in[2 + n];
    neumip_main<false><<<TOTAL / 256, 256, 0, stream>>>(uvs, level, tp, (float*)d_out);
  }
}

// Round 3
// 368.663 us; speedup vs baseline: 1.0364x; 1.0364x over previous
//
#include <hip/hip_runtime.h>

#define NL 5
#define CH 8
#define BATCH 4
#define HH 1024
#define WW 1024
#define HW (HH * WW)
#define TOTAL (BATCH * HW)

// Native clang vector types: required by __builtin_nontemporal_load/store.
typedef float vf2 __attribute__((ext_vector_type(2)));
typedef float vf4 __attribute__((ext_vector_type(4)));

struct TexPtrs { const float* t[NL]; };

struct TransposeArgs {
  const float* src[NL];
  float* dst[NL];
  int cnt[NL];
  int cum[NL + 1];
};

// Fused transpose of all mip levels: (C,R,R) -> (R,R,C) interleaved.
// One launch; 349184 texels = 1364 * 256 exactly.
__global__ __launch_bounds__(256) void transpose_all_kernel(TransposeArgs ta) {
  int i = blockIdx.x * blockDim.x + threadIdx.x;
  int L = 0;
#pragma unroll
  for (int k = 1; k < NL; ++k)
    if (i >= ta.cum[k]) L = k;
  int li = i - ta.cum[L];
  int n = ta.cnt[L];
  const float* s = ta.src[L];
  float v[CH];
#pragma unroll
  for (int c = 0; c < CH; ++c)
    v[c] = __builtin_nontemporal_load(s + (size_t)c * n + li);  // src never read again
  // dst WILL be read by the gather kernel: keep it cacheable.
  vf4* d = (vf4*)(ta.dst[L] + (size_t)li * CH);
  d[0] = (vf4){v[0], v[1], v[2], v[3]};
  d[1] = (vf4){v[4], v[5], v[6], v[7]};
}

__global__ __launch_bounds__(256) void neumip_main(
    const float* __restrict__ uvs, const float* __restrict__ level,
    TexPtrs tp, float* __restrict__ out) {
  int idx = blockIdx.x * blockDim.x + threadIdx.x;
  if (idx >= TOTAL) return;

  // Streaming inputs: nontemporal so they don't evict textures from L2.
  vf2 uv = __builtin_nontemporal_load((const vf2*)uvs + idx);
  float lvl = __builtin_nontemporal_load(level + idx);

  float fu = uv.x - truncf(uv.x);
  float fv = uv.y - truncf(uv.y);
  float cu = fu * 2.0f - 1.0f;
  float cv = fv * 2.0f - 1.0f;

  float fb = floorf(lvl);
  float alpha = lvl - fb;
  fb = fminf(fmaxf(fb, 0.0f), (float)(NL - 1));
  int l0 = (int)fb;
  int l1 = min(l0 + 1, NL - 1);

  float acc[CH];
#pragma unroll
  for (int c = 0; c < CH; ++c) acc[c] = 0.0f;

  int lv[2] = {l0, l1};
  float wgt[2] = {1.0f - alpha, alpha};

#pragma unroll
  for (int s = 0; s < 2; ++s) {
    int L = lv[s];
    int R = 512 >> L;
    float Rm1 = (float)(R - 1);
    float x = (cu + 1.0f) * 0.5f * Rm1;
    float y = (cv + 1.0f) * 0.5f * Rm1;
    float x0f = floorf(x);
    float y0f = floorf(y);
    float wx = x - x0f;
    float wy = y - y0f;
    int x0 = (int)x0f;
    int y0 = (int)y0f;
    x0 = max(x0, 0);
    y0 = max(y0, 0);
    int x1 = min(x0 + 1, R - 1);
    int y1 = min(y0 + 1, R - 1);

    float w = wgt[s];
    float w00 = (1.0f - wx) * (1.0f - wy) * w;
    float w01 = wx * (1.0f - wy) * w;
    float w10 = (1.0f - wx) * wy * w;
    float w11 = wx * wy * w;

    const vf4* t = (const vf4*)tp.t[L];
    size_t i00 = ((size_t)y0 * R + x0) * 2;
    size_t i01 = ((size_t)y0 * R + x1) * 2;
    size_t i10 = ((size_t)y1 * R + x0) * 2;
    size_t i11 = ((size_t)y1 * R + x1) * 2;
    vf4 a00 = t[i00], b00 = t[i00 + 1];
    vf4 a01 = t[i01], b01 = t[i01 + 1];
    vf4 a10 = t[i10], b10 = t[i10 + 1];
    vf4 a11 = t[i11], b11 = t[i11 + 1];
    acc[0] += a00.x * w00 + a01.x * w01 + a10.x * w10 + a11.x * w11;
    acc[1] += a00.y * w00 + a01.y * w01 + a10.y * w10 + a11.y * w11;
    acc[2] += a00.z * w00 + a01.z * w01 + a10.z * w10 + a11.z * w11;
    acc[3] += a00.w * w00 + a01.w * w01 + a10.w * w10 + a11.w * w11;
    acc[4] += b00.x * w00 + b01.x * w01 + b10.x * w10 + b11.x * w11;
    acc[5] += b00.y * w00 + b01.y * w01 + b10.y * w10 + b11.y * w11;
    acc[6] += b00.z * w00 + b01.z * w01 + b10.z * w10 + b11.z * w11;
    acc[7] += b00.w * w00 + b01.w * w01 + b10.w * w10 + b11.w * w11;
  }

  // out[b][c][h][w]; idx = b*HW + hw. Streaming output: nontemporal stores.
  int b = idx >> 20;  // HW = 1<<20
  int hw = idx & (HW - 1);
  float* o = out + ((size_t)b * CH) * HW + hw;
#pragma unroll
  for (int c = 0; c < CH; ++c)
    __builtin_nontemporal_store(acc[c], o + (size_t)c * HW);
}

extern "C" void kernel_launch(void* const* d_in, const int* in_sizes, int n_in,
                              void* d_out, int out_size, void* d_ws, size_t ws_size,
                              hipStream_t stream) {
  const float* uvs = (const float*)d_in[0];
  const float* level = (const float*)d_in[1];
  static const int res[NL] = {512, 256, 128, 64, 32};

  TransposeArgs ta;
  TexPtrs tp;
  float* cur = (float*)d_ws;
  int cum = 0;
  for (int n = 0; n < NL; ++n) {
    int cnt = res[n] * res[n];
    ta.src[n] = (const float*)d_in[2 + n];
    ta.dst[n] = cur;
    ta.cnt[n] = cnt;
    ta.cum[n] = cum;
    tp.t[n] = cur;
    cur += (size_t)cnt * CH;
    cum += cnt;
  }
  ta.cum[NL] = cum;  // 349184 = 1364 * 256

  transpose_all_kernel<<<cum / 256, 256, 0, stream>>>(ta);
  neumip_main<<<TOTAL / 256, 256, 0, stream>>>(uvs, level, tp, (float*)d_out);
}

// Round 5
// 312.213 us; speedup vs baseline: 1.2238x; 1.1808x over previous
//
#include <hip/hip_runtime.h>

#define NL 5
#define CH 8
#define BATCH 4
#define HH 1024
#define WW 1024
#define HW (HH * WW)
#define TOTAL (BATCH * HW)

// Native clang vector types (required by __builtin_nontemporal_*).
typedef float vf2 __attribute__((ext_vector_type(2)));
typedef _Float16 hf8 __attribute__((ext_vector_type(8)));  // one texel: 8ch fp16 = 16 B

struct TexPtrs { const _Float16* t[NL]; };

struct TransposeArgs {
  const float* src[NL];
  _Float16* dst[NL];
  int cnt[NL];
  int cum[NL + 1];
};

// Fused transpose+downconvert of all mip levels: (C,R,R) fp32 -> (R,R,C) fp16.
// 349184 texels = 1364 * 256 exactly.
__global__ __launch_bounds__(256) void transpose_all_kernel(TransposeArgs ta) {
  int i = blockIdx.x * blockDim.x + threadIdx.x;
  int L = 0;
#pragma unroll
  for (int k = 1; k < NL; ++k)
    if (i >= ta.cum[k]) L = k;
  int li = i - ta.cum[L];
  int n = ta.cnt[L];
  const float* s = ta.src[L];
  hf8 v;
#pragma unroll
  for (int c = 0; c < CH; ++c)
    v[c] = (_Float16)__builtin_nontemporal_load(s + (size_t)c * n + li);
  ((hf8*)ta.dst[L])[li] = v;  // gather kernel will read this: keep cacheable
}

__global__ __launch_bounds__(256) void neumip_main(
    const float* __restrict__ uvs, const float* __restrict__ level,
    TexPtrs tp, float* __restrict__ out) {
  int idx = blockIdx.x * blockDim.x + threadIdx.x;
  if (idx >= TOTAL) return;

  // Streaming inputs: nontemporal so they don't evict textures from L2.
  vf2 uv = __builtin_nontemporal_load((const vf2*)uvs + idx);
  float lvl = __builtin_nontemporal_load(level + idx);

  float fu = uv.x - truncf(uv.x);
  float fv = uv.y - truncf(uv.y);
  float cu = fu * 2.0f - 1.0f;
  float cv = fv * 2.0f - 1.0f;

  float fb = floorf(lvl);
  float alpha = lvl - fb;
  fb = fminf(fmaxf(fb, 0.0f), (float)(NL - 1));
  int l0 = (int)fb;
  int l1 = min(l0 + 1, NL - 1);

  float acc[CH];
#pragma unroll
  for (int c = 0; c < CH; ++c) acc[c] = 0.0f;

  float wgt[2] = {1.0f - alpha, alpha};

#pragma unroll
  for (int s = 0; s < 2; ++s) {
    int L = (s == 0) ? l0 : l1;
    int R = 512 >> L;
    float Rm1 = (float)(R - 1);
    float x = (cu + 1.0f) * 0.5f * Rm1;
    float y = (cv + 1.0f) * 0.5f * Rm1;
    float x0f = floorf(x);
    float y0f = floorf(y);
    float wx = x - x0f;
    float wy = y - y0f;
    int x0 = (int)x0f;
    int y0 = (int)y0f;
    x0 = max(x0, 0);
    y0 = max(y0, 0);
    int x1 = min(x0 + 1, R - 1);
    int y1 = min(y0 + 1, R - 1);

    float w = wgt[s];
    float w00 = (1.0f - wx) * (1.0f - wy) * w;
    float w01 = wx * (1.0f - wy) * w;
    float w10 = (1.0f - wx) * wy * w;
    float w11 = wx * wy * w;

    // One 16 B load per corner (8 fp16 channels interleaved).
    const hf8* t = reinterpret_cast<const hf8*>(tp.t[L]);
    hf8 c00 = t[(size_t)y0 * R + x0];
    hf8 c01 = t[(size_t)y0 * R + x1];
    hf8 c10 = t[(size_t)y1 * R + x0];
    hf8 c11 = t[(size_t)y1 * R + x1];
#pragma unroll
    for (int c = 0; c < CH; ++c)
      acc[c] += (float)c00[c] * w00 + (float)c01[c] * w01 +
                (float)c10[c] * w10 + (float)c11[c] * w11;
  }

  // out[b][c][h][w]; idx = b*HW + hw. Streaming output: nontemporal stores.
  int b = idx >> 20;  // HW = 1<<20
  int hw = idx & (HW - 1);
  float* o = out + ((size_t)b * CH) * HW + hw;
#pragma unroll
  for (int c = 0; c < CH; ++c)
    __builtin_nontemporal_store(acc[c], o + (size_t)c * HW);
}

extern "C" void kernel_launch(void* const* d_in, const int* in_sizes, int n_in,
                              void* d_out, int out_size, void* d_ws, size_t ws_size,
                              hipStream_t stream) {
  const float* uvs = (const float*)d_in[0];
  const float* level = (const float*)d_in[1];
  static const int res[NL] = {512, 256, 128, 64, 32};

  TransposeArgs ta;
  TexPtrs tp;
  _Float16* cur = (_Float16*)d_ws;
  int cum = 0;
  for (int n = 0; n < NL; ++n) {
    int cnt = res[n] * res[n];
    ta.src[n] = (const float*)d_in[2 + n];
    ta.dst[n] = cur;
    ta.cnt[n] = cnt;
    ta.cum[n] = cum;
    tp.t[n] = cur;
    cur += (size_t)cnt * CH;
    cum += cnt;
  }
  ta.cum[NL] = cum;  // 349184 = 1364 * 256

  transpose_all_kernel<<<cum / 256, 256, 0, stream>>>(ta);
  neumip_main<<<TOTAL / 256, 256, 0, stream>>>(uvs, level, tp, (float*)d_out);
}